// Round 5
// baseline (95.682 us; speedup 1.0000x reference)
//
#include <hip/hip_runtime.h>
#include <hip/hip_fp16.h>

// ARAP forward, f16-packed batch-interleaved gathers + non-temporal streaming.
// packed[vertex][batch] = 16-B record (f16 x1,y1,z1,x2,y2,z2,pad,pad): the 4
// lanes handling one vertex's 4 batches gather the SAME 64-B line (one fully
// used line per vertex gather; 4 MB working set == per-XCD L2 size).
// Edge streams (nbrList/wMat) are nontemporal loads and the 12.6 MB output is
// nontemporal stores, so the L2 stays dedicated to the random gather set.
// Math: one-pass S/A/Q accumulation, polar-Newton rotation (== det-corrected
// SVD for det(S)>0), energy identity E_r = Q_r - 2 Σc R[r][c]S[c][r] + rowRᵀA rowR.

__global__ void __launch_bounds__(256) arap_pack_kernel(
    const float* __restrict__ xyz1, const float* __restrict__ xyz2,
    uint4* __restrict__ packed, int B, int N)
{
    const int t = blockIdx.x * blockDim.x + threadIdx.x;
    if (t >= B * N) return;
    const int i = t / B;
    const int b = t - i * B;
    const float* a = xyz1 + ((size_t)b * N + i) * 3;
    const float* c = xyz2 + ((size_t)b * N + i) * 3;
    const __half2 h0 = __floats2half2_rn(a[0], a[1]);
    const __half2 h1 = __floats2half2_rn(a[2], c[0]);
    const __half2 h2 = __floats2half2_rn(c[1], c[2]);
    uint4 r;
    r.x = *(const unsigned int*)&h0;
    r.y = *(const unsigned int*)&h1;
    r.z = *(const unsigned int*)&h2;
    r.w = 0u;
    packed[t] = r;   // keep in cache: fwd kernel gathers from this
}

__global__ void __launch_bounds__(256) arap_fwd_kernel(
    const uint4* __restrict__ packed,   // [N][B] 16-B f16 records
    const int*   __restrict__ nbrList,  // [E]
    const int*   __restrict__ numN,     // [N]
    const int*   __restrict__ accN,     // [N] CSR starts
    const float* __restrict__ wMat,     // [E]
    const float* __restrict__ arapW,    // [1]
    float* __restrict__ out,            // energies [B*N*3] then rotations [B*N*9]
    int B, int N)
{
    const int tid = blockIdx.x * blockDim.x + threadIdx.x;
    const int total = B * N;
    if (tid >= total) return;
    const int i = tid / B;          // vertex
    const int b = tid - i * B;      // batch (fast across lanes)

    const uint4 pr = packed[tid];
    const float2 pf0 = __half22float2(*(const __half2*)&pr.x);
    const float2 pf1 = __half22float2(*(const __half2*)&pr.y);
    const float2 pf2 = __half22float2(*(const __half2*)&pr.z);
    const float p1x = pf0.x, p1y = pf0.y, p1z = pf1.x;
    const float p2x = pf1.y, p2y = pf2.x, p2z = pf2.y;

    const int start = accN[i];
    const int cnt   = numN[i];

    float S00=0.f,S01=0.f,S02=0.f,S10=0.f,S11=0.f,S12=0.f,S20=0.f,S21=0.f,S22=0.f;
    float A00=0.f,A01=0.f,A02=0.f,A11=0.f,A12=0.f,A22=0.f;
    float Qx=0.f,Qy=0.f,Qz=0.f;

    auto edge_body = [&](int e) {
        const int j   = __builtin_nontemporal_load(nbrList + e);  // stream, no reuse
        const float w = __builtin_nontemporal_load(wMat + e);
        const uint4 rec = packed[(size_t)j * B + b];              // cacheable gather
        const float2 f0 = __half22float2(*(const __half2*)&rec.x);
        const float2 f1 = __half22float2(*(const __half2*)&rec.y);
        const float2 f2 = __half22float2(*(const __half2*)&rec.z);
        const float d1x = p1x - f0.x, d1y = p1y - f0.y, d1z = p1z - f1.x;
        const float d2x = p2x - f1.y, d2y = p2y - f2.x, d2z = p2z - f2.y;
        const float w1x = w*d1x, w1y = w*d1y, w1z = w*d1z;
        S00 = fmaf(w1x, d2x, S00); S01 = fmaf(w1x, d2y, S01); S02 = fmaf(w1x, d2z, S02);
        S10 = fmaf(w1y, d2x, S10); S11 = fmaf(w1y, d2y, S11); S12 = fmaf(w1y, d2z, S12);
        S20 = fmaf(w1z, d2x, S20); S21 = fmaf(w1z, d2y, S21); S22 = fmaf(w1z, d2z, S22);
        A00 = fmaf(w1x, d1x, A00); A01 = fmaf(w1x, d1y, A01); A02 = fmaf(w1x, d1z, A02);
        A11 = fmaf(w1y, d1y, A11); A12 = fmaf(w1y, d1z, A12); A22 = fmaf(w1z, d1z, A22);
        const float w2x = w*d2x, w2y = w*d2y, w2z = w*d2z;
        Qx = fmaf(w2x, d2x, Qx); Qy = fmaf(w2y, d2y, Qy); Qz = fmaf(w2z, d2z, Qz);
    };

    if (cnt == 16) {
        #pragma unroll
        for (int k = 0; k < 16; ++k) edge_body(start + k);
    } else {
        for (int k = 0; k < cnt; ++k) edge_body(start + k);
    }

    // ---- polar factor of X = S^T via scaled Newton ----
    float X00=S00, X01=S10, X02=S20;
    float X10=S01, X11=S11, X12=S21;
    float X20=S02, X21=S12, X22=S22;

    for (int it = 0; it < 6; ++it) {
        const float c00 =  (X11*X22 - X12*X21);
        const float c01 = -(X10*X22 - X12*X20);
        const float c02 =  (X10*X21 - X11*X20);
        const float c10 = -(X01*X22 - X02*X21);
        const float c11 =  (X00*X22 - X02*X20);
        const float c12 = -(X00*X21 - X01*X20);
        const float c20 =  (X01*X12 - X02*X11);
        const float c21 = -(X00*X12 - X02*X10);
        const float c22 =  (X00*X11 - X01*X10);
        const float det = X00*c00 + X01*c01 + X02*c02;
        const float ad  = fabsf(det);
        if (ad < 1e-30f) break;
        const float g  = exp2f(-(1.0f/3.0f) * log2f(ad));   // |det|^(-1/3)
        const float a  = 0.5f * g;
        const float bb = copysignf(0.5f * g * g, det);
        X00 = a*X00 + bb*c00; X01 = a*X01 + bb*c01; X02 = a*X02 + bb*c02;
        X10 = a*X10 + bb*c10; X11 = a*X11 + bb*c11; X12 = a*X12 + bb*c12;
        X20 = a*X20 + bb*c20; X21 = a*X21 + bb*c21; X22 = a*X22 + bb*c22;
    }
    // X == R (row-major)

    // ---- energies via identity ----
    const float crx = X00*S00 + X01*S10 + X02*S20;
    const float cry = X10*S01 + X11*S11 + X12*S21;
    const float crz = X20*S02 + X21*S12 + X22*S22;

    float tx, ty, tz;
    tx = A00*X00 + A01*X01 + A02*X02;
    ty = A01*X00 + A11*X01 + A12*X02;
    tz = A02*X00 + A12*X01 + A22*X02;
    const float qdx = X00*tx + X01*ty + X02*tz;
    tx = A00*X10 + A01*X11 + A02*X12;
    ty = A01*X10 + A11*X11 + A12*X12;
    tz = A02*X10 + A12*X11 + A22*X12;
    const float qdy = X10*tx + X11*ty + X12*tz;
    tx = A00*X20 + A01*X21 + A02*X22;
    ty = A01*X20 + A11*X21 + A12*X22;
    tz = A02*X20 + A12*X21 + A22*X22;
    const float qdz = X20*tx + X21*ty + X22*tz;

    const float aw = arapW[0];
    const float Ex = fmaxf(0.f, Qx - 2.f*crx + qdx);
    const float Ey = fmaxf(0.f, Qy - 2.f*cry + qdy);
    const float Ez = fmaxf(0.f, Qz - 2.f*crz + qdz);

    // nontemporal output stores: 12.6 MB stream with zero reuse — keep it
    // out of L2 so the packed gather set stays resident.
    float* eo = out + ((size_t)b * N + i) * 3;
    __builtin_nontemporal_store(aw * Ex, eo + 0);
    __builtin_nontemporal_store(aw * Ey, eo + 1);
    __builtin_nontemporal_store(aw * Ez, eo + 2);

    float* ro = out + (size_t)total * 3 + ((size_t)b * N + i) * 9;
    __builtin_nontemporal_store(X00, ro + 0);
    __builtin_nontemporal_store(X01, ro + 1);
    __builtin_nontemporal_store(X02, ro + 2);
    __builtin_nontemporal_store(X10, ro + 3);
    __builtin_nontemporal_store(X11, ro + 4);
    __builtin_nontemporal_store(X12, ro + 5);
    __builtin_nontemporal_store(X20, ro + 6);
    __builtin_nontemporal_store(X21, ro + 7);
    __builtin_nontemporal_store(X22, ro + 8);
}

extern "C" void kernel_launch(void* const* d_in, const int* in_sizes, int n_in,
                              void* d_out, int out_size, void* d_ws, size_t ws_size,
                              hipStream_t stream) {
    const float* xyz1 = (const float*)d_in[0];
    const float* xyz2 = (const float*)d_in[1];
    const int*   nbr  = (const int*)d_in[2];
    const int*   numN = (const int*)d_in[3];
    const int*   accN = (const int*)d_in[4];
    const float* wMat = (const float*)d_in[5];
    const float* aW   = (const float*)d_in[6];

    const int N = in_sizes[3];
    const int B = in_sizes[0] / (N * 3);
    const int total = B * N;

    uint4* packed = (uint4*)d_ws;   // [N][B] 16-B f16 records (4 MB)
    const int block = 256;
    const int grid  = (total + block - 1) / block;

    hipLaunchKernelGGL(arap_pack_kernel, dim3(grid), dim3(block), 0, stream,
                       xyz1, xyz2, packed, B, N);
    hipLaunchKernelGGL(arap_fwd_kernel, dim3(grid), dim3(block), 0, stream,
                       packed, nbr, numN, accN, wMat, aW,
                       (float*)d_out, B, N);
}

// Round 6
// 93.076 us; speedup vs baseline: 1.0280x; 1.0280x over previous
//
#include <hip/hip_runtime.h>
#include <hip/hip_fp16.h>

// ARAP forward, f16-packed batch-interleaved gathers (R4 configuration — the
// non-temporal variant of R5 regressed 93.4->95.7 us and is reverted).
// packed[vertex][batch] = 16-B record (f16 x1,y1,z1,x2,y2,z2,pad,pad).
// The 4 lanes handling one vertex's 4 batches gather the SAME 64-B line ->
// one fully used cache line per vertex gather, 4 MB working set (per-XCD L2).
// Math: one-pass S/A/Q accumulation, polar-Newton rotation (== det-corrected
// SVD for det(S)>0), energy identity E_r = Q_r - 2 Σc R[r][c]S[c][r] + rowRᵀA rowR.

__global__ void __launch_bounds__(256) arap_pack_kernel(
    const float* __restrict__ xyz1, const float* __restrict__ xyz2,
    uint4* __restrict__ packed, int B, int N)
{
    const int t = blockIdx.x * blockDim.x + threadIdx.x;
    if (t >= B * N) return;
    const int i = t / B;
    const int b = t - i * B;
    const float* a = xyz1 + ((size_t)b * N + i) * 3;
    const float* c = xyz2 + ((size_t)b * N + i) * 3;
    const __half2 h0 = __floats2half2_rn(a[0], a[1]);
    const __half2 h1 = __floats2half2_rn(a[2], c[0]);
    const __half2 h2 = __floats2half2_rn(c[1], c[2]);
    uint4 r;
    r.x = *(const unsigned int*)&h0;
    r.y = *(const unsigned int*)&h1;
    r.z = *(const unsigned int*)&h2;
    r.w = 0u;
    packed[t] = r;
}

__global__ void __launch_bounds__(256) arap_fwd_kernel(
    const uint4* __restrict__ packed,   // [N][B] 16-B f16 records
    const int*   __restrict__ nbrList,  // [E]
    const int*   __restrict__ numN,     // [N]
    const int*   __restrict__ accN,     // [N] CSR starts
    const float* __restrict__ wMat,     // [E]
    const float* __restrict__ arapW,    // [1]
    float* __restrict__ out,            // energies [B*N*3] then rotations [B*N*9]
    int B, int N)
{
    const int tid = blockIdx.x * blockDim.x + threadIdx.x;
    const int total = B * N;
    if (tid >= total) return;
    const int i = tid / B;          // vertex
    const int b = tid - i * B;      // batch (fast across lanes)

    const uint4 pr = packed[tid];
    const float2 pf0 = __half22float2(*(const __half2*)&pr.x);
    const float2 pf1 = __half22float2(*(const __half2*)&pr.y);
    const float2 pf2 = __half22float2(*(const __half2*)&pr.z);
    const float p1x = pf0.x, p1y = pf0.y, p1z = pf1.x;
    const float p2x = pf1.y, p2y = pf2.x, p2z = pf2.y;

    const int start = accN[i];
    const int cnt   = numN[i];

    float S00=0.f,S01=0.f,S02=0.f,S10=0.f,S11=0.f,S12=0.f,S20=0.f,S21=0.f,S22=0.f;
    float A00=0.f,A01=0.f,A02=0.f,A11=0.f,A12=0.f,A22=0.f;
    float Qx=0.f,Qy=0.f,Qz=0.f;

    auto edge_body = [&](int e) {
        const int j = nbrList[e];
        const float w = wMat[e];
        const uint4 rec = packed[(size_t)j * B + b];
        const float2 f0 = __half22float2(*(const __half2*)&rec.x);
        const float2 f1 = __half22float2(*(const __half2*)&rec.y);
        const float2 f2 = __half22float2(*(const __half2*)&rec.z);
        const float d1x = p1x - f0.x, d1y = p1y - f0.y, d1z = p1z - f1.x;
        const float d2x = p2x - f1.y, d2y = p2y - f2.x, d2z = p2z - f2.y;
        const float w1x = w*d1x, w1y = w*d1y, w1z = w*d1z;
        S00 = fmaf(w1x, d2x, S00); S01 = fmaf(w1x, d2y, S01); S02 = fmaf(w1x, d2z, S02);
        S10 = fmaf(w1y, d2x, S10); S11 = fmaf(w1y, d2y, S11); S12 = fmaf(w1y, d2z, S12);
        S20 = fmaf(w1z, d2x, S20); S21 = fmaf(w1z, d2y, S21); S22 = fmaf(w1z, d2z, S22);
        A00 = fmaf(w1x, d1x, A00); A01 = fmaf(w1x, d1y, A01); A02 = fmaf(w1x, d1z, A02);
        A11 = fmaf(w1y, d1y, A11); A12 = fmaf(w1y, d1z, A12); A22 = fmaf(w1z, d1z, A22);
        const float w2x = w*d2x, w2y = w*d2y, w2z = w*d2z;
        Qx = fmaf(w2x, d2x, Qx); Qy = fmaf(w2y, d2y, Qy); Qz = fmaf(w2z, d2z, Qz);
    };

    if (cnt == 16) {
        #pragma unroll
        for (int k = 0; k < 16; ++k) edge_body(start + k);
    } else {
        for (int k = 0; k < cnt; ++k) edge_body(start + k);
    }

    // ---- polar factor of X = S^T via scaled Newton ----
    float X00=S00, X01=S10, X02=S20;
    float X10=S01, X11=S11, X12=S21;
    float X20=S02, X21=S12, X22=S22;

    for (int it = 0; it < 6; ++it) {
        const float c00 =  (X11*X22 - X12*X21);
        const float c01 = -(X10*X22 - X12*X20);
        const float c02 =  (X10*X21 - X11*X20);
        const float c10 = -(X01*X22 - X02*X21);
        const float c11 =  (X00*X22 - X02*X20);
        const float c12 = -(X00*X21 - X01*X20);
        const float c20 =  (X01*X12 - X02*X11);
        const float c21 = -(X00*X12 - X02*X10);
        const float c22 =  (X00*X11 - X01*X10);
        const float det = X00*c00 + X01*c01 + X02*c02;
        const float ad  = fabsf(det);
        if (ad < 1e-30f) break;
        const float g  = exp2f(-(1.0f/3.0f) * log2f(ad));   // |det|^(-1/3)
        const float a  = 0.5f * g;
        const float bb = copysignf(0.5f * g * g, det);
        X00 = a*X00 + bb*c00; X01 = a*X01 + bb*c01; X02 = a*X02 + bb*c02;
        X10 = a*X10 + bb*c10; X11 = a*X11 + bb*c11; X12 = a*X12 + bb*c12;
        X20 = a*X20 + bb*c20; X21 = a*X21 + bb*c21; X22 = a*X22 + bb*c22;
    }
    // X == R (row-major)

    // ---- energies via identity ----
    const float crx = X00*S00 + X01*S10 + X02*S20;
    const float cry = X10*S01 + X11*S11 + X12*S21;
    const float crz = X20*S02 + X21*S12 + X22*S22;

    float tx, ty, tz;
    tx = A00*X00 + A01*X01 + A02*X02;
    ty = A01*X00 + A11*X01 + A12*X02;
    tz = A02*X00 + A12*X01 + A22*X02;
    const float qdx = X00*tx + X01*ty + X02*tz;
    tx = A00*X10 + A01*X11 + A02*X12;
    ty = A01*X10 + A11*X11 + A12*X12;
    tz = A02*X10 + A12*X11 + A22*X12;
    const float qdy = X10*tx + X11*ty + X12*tz;
    tx = A00*X20 + A01*X21 + A02*X22;
    ty = A01*X20 + A11*X21 + A12*X22;
    tz = A02*X20 + A12*X21 + A22*X22;
    const float qdz = X20*tx + X21*ty + X22*tz;

    const float aw = arapW[0];
    const float Ex = fmaxf(0.f, Qx - 2.f*crx + qdx);
    const float Ey = fmaxf(0.f, Qy - 2.f*cry + qdy);
    const float Ez = fmaxf(0.f, Qz - 2.f*crz + qdz);

    float* eo = out + ((size_t)b * N + i) * 3;
    eo[0] = aw * Ex; eo[1] = aw * Ey; eo[2] = aw * Ez;

    float* ro = out + (size_t)total * 3 + ((size_t)b * N + i) * 9;
    ro[0]=X00; ro[1]=X01; ro[2]=X02;
    ro[3]=X10; ro[4]=X11; ro[5]=X12;
    ro[6]=X20; ro[7]=X21; ro[8]=X22;
}

extern "C" void kernel_launch(void* const* d_in, const int* in_sizes, int n_in,
                              void* d_out, int out_size, void* d_ws, size_t ws_size,
                              hipStream_t stream) {
    const float* xyz1 = (const float*)d_in[0];
    const float* xyz2 = (const float*)d_in[1];
    const int*   nbr  = (const int*)d_in[2];
    const int*   numN = (const int*)d_in[3];
    const int*   accN = (const int*)d_in[4];
    const float* wMat = (const float*)d_in[5];
    const float* aW   = (const float*)d_in[6];

    const int N = in_sizes[3];
    const int B = in_sizes[0] / (N * 3);
    const int total = B * N;

    uint4* packed = (uint4*)d_ws;   // [N][B] 16-B f16 records (4 MB)
    const int block = 256;
    const int grid  = (total + block - 1) / block;

    hipLaunchKernelGGL(arap_pack_kernel, dim3(grid), dim3(block), 0, stream,
                       xyz1, xyz2, packed, B, N);
    hipLaunchKernelGGL(arap_fwd_kernel, dim3(grid), dim3(block), 0, stream,
                       packed, nbr, numN, accN, wMat, aW,
                       (float*)d_out, B, N);
}